// Round 4
// baseline (1212.823 us; speedup 1.0000x reference)
//
#include <hip/hip_runtime.h>

#define C 128

typedef __attribute__((ext_vector_type(4))) float float4v;
typedef _Float16 half8v __attribute__((ext_vector_type(8)));
typedef _Float16 half4v __attribute__((ext_vector_type(4)));

// ---------------- degree count ------------------------------------------
__global__ void k_degree(const int* __restrict__ col, int* __restrict__ cnt, int E) {
  int e = blockIdx.x * blockDim.x + threadIdx.x;
  if (e < E) atomicAdd(&cnt[col[e]], 1);
}

// ---------------- hierarchical scan (3 kernels, all wide) ---------------
__global__ void k_scan_part(const int* __restrict__ cnt, int* __restrict__ part,
                            int N) {
  __shared__ int sb[256];
  int t = threadIdx.x;
  int i = blockIdx.x * 256 + t;
  sb[t] = (i < N) ? cnt[i] : 0;
  __syncthreads();
#pragma unroll
  for (int off = 128; off > 0; off >>= 1) {
    if (t < off) sb[t] += sb[t + off];
    __syncthreads();
  }
  if (t == 0) part[blockIdx.x] = sb[0];
}

__global__ void k_scan_mid(int* __restrict__ part, int P) {
  __shared__ int sb[256];
  int t = threadIdx.x;
  int v = (t < P) ? part[t] : 0;
  sb[t] = v;
  __syncthreads();
#pragma unroll
  for (int off = 1; off < 256; off <<= 1) {
    int u = (t >= off) ? sb[t - off] : 0;
    __syncthreads();
    sb[t] += u;
    __syncthreads();
  }
  if (t < P) part[t] = sb[t] - v;  // exclusive
}

__global__ void k_scan_fin(const int* __restrict__ cnt, const int* __restrict__ part,
                           float* __restrict__ dis, int* __restrict__ indptr,
                           int* __restrict__ cursor, int N) {
  __shared__ int sb[256];
  int t = threadIdx.x;
  int i = blockIdx.x * 256 + t;
  int v = (i < N) ? cnt[i] : 0;
  sb[t] = v;
  __syncthreads();
#pragma unroll
  for (int off = 1; off < 256; off <<= 1) {
    int u = (t >= off) ? sb[t - off] : 0;
    __syncthreads();
    sb[t] += u;
    __syncthreads();
  }
  int run = part[blockIdx.x] + sb[t] - v;  // exclusive prefix
  if (i < N) {
    indptr[i] = run;
    cursor[i] = run;
    dis[i] = rsqrtf((float)(v + 1));  // +1 self loop
    if (i == N - 1) indptr[N] = run + v;
  }
}

// ---------------- CSR fill (dst-sorted) ---------------------------------
// v2: only emeta is scatter-written (epair removed; col id is regenerated
// by k_colfill as a coalesced segmented fill) -> halves the 64B-line
// write amplification that made this kernel write-bound.
__global__ void k_csrfill(const int* __restrict__ row, const int* __restrict__ col,
                          const float* __restrict__ dis, int* __restrict__ cursor,
                          int2* __restrict__ emeta, int* __restrict__ inv, int E) {
  int e = blockIdx.x * blockDim.x + threadIdx.x;
  if (e >= E) return;
  int r = row[e], c = col[e];
  int pos = atomicAdd(&cursor[c], 1);
  float nrm = dis[r] * dis[c];
  emeta[pos] = make_int2(r, __float_as_int(nrm));
  inv[e] = pos;
}

// ---------------- col-per-position fill (coalesced) ----------------------
// wave per node: colcsr[indptr[w]..indptr[w+1]) = w. Streaming writes.
__global__ void k_colfill(const int* __restrict__ indptr, int* __restrict__ colcsr,
                          int N) {
  int w = (blockIdx.x * 256 + threadIdx.x) >> 6;
  int lane = threadIdx.x & 63;
  if (w >= N) return;
  int s = indptr[w], e = indptr[w + 1];
  for (int i = s + lane; i < e; i += 64) colcsr[i] = w;
}

// ---------------- x fp32 -> fp16 ----------------------------------------
__global__ void k_cvt(const float* __restrict__ x, _Float16* __restrict__ xh, int n4) {
  int i = blockIdx.x * 256 + threadIdx.x;
  if (i >= n4) return;
  float4 v = ((const float4*)x)[i];
  half4v o = {(_Float16)v.x, (_Float16)v.y, (_Float16)v.z, (_Float16)v.w};
  *(half4v*)(xh + i * 4) = o;
}

// ---------------- W1 -> fp16 fragment-major table (fc1) ------------------
__global__ void k_prepwf(const float* __restrict__ W1, _Float16* __restrict__ Wf) {
  int idx = blockIdx.x * 256 + threadIdx.x;  // 16384
  int e = idx & 7, lane = (idx >> 3) & 63, j = (idx >> 9) & 7, kk = idx >> 12;
  int n = j * 16 + (lane & 15);
  int k = (kk * 4 + (lane >> 4)) * 8 + e;
  Wf[idx] = (_Float16)W1[k * C + n];
}

// ------- conv/fc0 W -> fragment-major fp16 hi + scaled-lo (10 mats) ------
// lo = fp16((W - hi) * 4096) keeps residual normal; epilogue recombines
// acc_h + acc_l/4096 -> fp32-equivalent W.
__global__ void k_prepw2(const float* __restrict__ convs_W,
                         const float* __restrict__ fc0_W,
                         _Float16* __restrict__ Wfh, _Float16* __restrict__ Wfl) {
  int g = blockIdx.x * 256 + threadIdx.x;  // [0, 10*16384)
  int mat = g >> 14, idx = g & 16383;
  int e = idx & 7, lane = (idx >> 3) & 63, j = (idx >> 9) & 7, kk = idx >> 12;
  int n = j * 16 + (lane & 15);
  int k = (kk * 4 + (lane >> 4)) * 8 + e;
  const float* src = (mat < 8) ? convs_W + ((size_t)mat << 14)
                               : fc0_W + ((size_t)(mat - 8) << 14);
  float v = src[k * C + n];
  _Float16 h = (_Float16)v;
  Wfh[g] = h;
  Wfl[g] = (_Float16)((v - (float)h) * 4096.f);
}

// ---------------- aggregation (fp16 h -> fp16 agg) -----------------------
// Wave per node. v3: self-term load moved to epilogue (cuts ~5 live VGPRs)
// and launch_bounds(256,8) pins <=64 VGPR so 8 waves/SIMD are resident --
// max latency hiding for the random-row gather that dominates this kernel.
// emeta pipelined one 16-edge chunk ahead, non-temporal (streamed once).
__global__ __launch_bounds__(256, 8)
void k_agg(const _Float16* __restrict__ h, const int* __restrict__ indptr,
           const int2* __restrict__ emeta, const float* __restrict__ dis,
           _Float16* __restrict__ agg, int N) {
  int w = (blockIdx.x * 256 + threadIdx.x) >> 6;
  int lane = threadIdx.x & 63;
  if (w >= N) return;
  int g16 = lane >> 4, c8 = lane & 15;
  int s = indptr[w], e = indptr[w + 1];

  float acc[8];
#pragma unroll
  for (int j = 0; j < 8; ++j) acc[j] = 0.f;

  int i = s;
  long long mc[4];
  if (i + 16 <= e) {
#pragma unroll
    for (int u = 0; u < 4; ++u)
      mc[u] = __builtin_nontemporal_load(
          (const long long*)&emeta[i + u * 4 + g16]);
  }
  for (; i + 16 <= e;) {
    int inext = i + 16;
    bool hn = (inext + 16 <= e);
    long long mn[4];
    if (hn) {
#pragma unroll
      for (int u = 0; u < 4; ++u)
        mn[u] = __builtin_nontemporal_load(
            (const long long*)&emeta[inext + u * 4 + g16]);
    }
    half8v hv[4];
#pragma unroll
    for (int u = 0; u < 4; ++u) {
      int srcn = (int)(mc[u] & 0xffffffffLL);
      hv[u] = *(const half8v*)(h + (size_t)srcn * C + c8 * 8);
    }
#pragma unroll
    for (int u = 0; u < 4; ++u) {
      float nn = __int_as_float((int)(mc[u] >> 32));
#pragma unroll
      for (int j = 0; j < 8; ++j) acc[j] += nn * (float)hv[u][j];
    }
    if (hn) {
#pragma unroll
      for (int u = 0; u < 4; ++u) mc[u] = mn[u];
    }
    i = inext;
  }
  for (; i + 4 <= e; i += 4) {
    long long m = __builtin_nontemporal_load((const long long*)&emeta[i + g16]);
    int srcn = (int)(m & 0xffffffffLL);
    half8v hv = *(const half8v*)(h + (size_t)srcn * C + c8 * 8);
    float nn = __int_as_float((int)(m >> 32));
#pragma unroll
    for (int j = 0; j < 8; ++j) acc[j] += nn * (float)hv[j];
  }
  if (i < e) {  // tail 1..3: out-of-range lanes use norm 0
    int idx = i + g16;
    int srcn = w;
    float nn = 0.f;
    if (idx < e) {
      long long m = __builtin_nontemporal_load((const long long*)&emeta[idx]);
      srcn = (int)(m & 0xffffffffLL);
      nn = __int_as_float((int)(m >> 32));
    }
    half8v hv = *(const half8v*)(h + (size_t)srcn * C + c8 * 8);
#pragma unroll
    for (int j = 0; j < 8; ++j) acc[j] += nn * (float)hv[j];
  }
#pragma unroll
  for (int j = 0; j < 8; ++j) {
    acc[j] += __shfl_xor(acc[j], 16, 64);
    acc[j] += __shfl_xor(acc[j], 32, 64);
  }
  if (lane < 16) {
    float dv = dis[w];
    float dv2 = dv * dv;
    half8v hs = *(const half8v*)(h + (size_t)w * C + lane * 8);
    half8v o;
#pragma unroll
    for (int j = 0; j < 8; ++j) o[j] = (_Float16)(acc[j] + dv2 * (float)hs[j]);
    *(half8v*)(agg + (size_t)w * C + lane * 8) = o;
  }
}

// ---------------- streaming f16 MFMA GEMM (no LDS, no barrier) ----------
__global__ __launch_bounds__(256, 4)
void k_gemm_f16(const _Float16* __restrict__ A,
                const _Float16* __restrict__ Wfh, const _Float16* __restrict__ Wfl,
                const float* __restrict__ bias, const _Float16* __restrict__ skip,
                _Float16* __restrict__ out, int M, int relu) {
  int t = threadIdx.x;
  int r0 = blockIdx.x * 64;
  int w = t >> 6, lane = t & 63;
  int m0 = w * 16, lm = lane & 15, lq = lane >> 4;
  int row = r0 + m0 + lm;
  if (row >= M) row = M - 1;
  const _Float16* Ar = A + (size_t)row * C;

  float4v acch[8], accl[8];
#pragma unroll
  for (int j = 0; j < 8; ++j) {
    acch[j] = (float4v){0.f, 0.f, 0.f, 0.f};
    accl[j] = (float4v){0.f, 0.f, 0.f, 0.f};
  }
#pragma unroll
  for (int kk = 0; kk < 4; ++kk) {
    half8v a = *(const half8v*)(Ar + kk * 32 + lq * 8);
#pragma unroll
    for (int j = 0; j < 8; ++j) {
      int fi = ((kk * 8 + j) * 64 + lane) << 3;
      half8v bh = *(const half8v*)(Wfh + fi);
      half8v bl = *(const half8v*)(Wfl + fi);
      acch[j] = __builtin_amdgcn_mfma_f32_16x16x32_f16(a, bh, acch[j], 0, 0, 0);
      accl[j] = __builtin_amdgcn_mfma_f32_16x16x32_f16(a, bl, accl[j], 0, 0, 0);
    }
  }
#pragma unroll
  for (int j = 0; j < 8; ++j) {
    int n = j * 16 + lm;
    float bv = bias ? bias[n] : 0.f;
#pragma unroll
    for (int r = 0; r < 4; ++r) {
      int m = r0 + m0 + lq * 4 + r;
      if (m >= M) continue;
      float v = acch[j][r] + accl[j][r] * (1.f / 4096.f) + bv;
      if (skip) v += (float)skip[(size_t)m * C + n];
      if (relu) v = fmaxf(v, 0.f);
      out[(size_t)m * C + n] = (_Float16)v;
    }
  }
}

// ---------------- fused edge MLP (fp16, CSR order, LDS weights) ----------
// fc1 fragment table (32KB) staged once per block in LDS; 32 edges/wave;
// (r,c) come from emeta.x (already scatter-written for agg) + colcsr
// (coalesced segmented fill) -- epair array eliminated.
__global__ __launch_bounds__(256, 4)
void k_edge(const _Float16* __restrict__ P, const _Float16* __restrict__ Q,
            const int2* __restrict__ emeta, const int* __restrict__ colcsr,
            const _Float16* __restrict__ Wf,
            const float* __restrict__ b1, const float* __restrict__ w2,
            const float* __restrict__ b2, float* __restrict__ tmpout, int E) {
  __shared__ __align__(16) _Float16 WL[16384];
  int t = threadIdx.x;
#pragma unroll
  for (int it = 0; it < 8; ++it) {
    int off = it * 2048 + t * 8;  // 4KB per iter, lane-major: conflict-free
    *(half8v*)(WL + off) = *(const half8v*)(Wf + off);
  }

  int w = t >> 6, lane = t & 63;
  int lm = lane & 15, lq = lane >> 4;
  int base = blockIdx.x * 128 + w * 32;  // wave's 32-edge range

  // gather + fuse: a[tile][kk] = relu(P[src]+Q[dst]) fragments
  half8v a[2][4];
#pragma unroll
  for (int tt = 0; tt < 2; ++tt) {
    int p = base + tt * 16 + lm;
    int pc = (p < E) ? p : (E - 1);
    long long ev = __builtin_nontemporal_load((const long long*)&emeta[pc]);
    int rx = (int)(ev & 0xffffffffLL);
    int ry = __builtin_nontemporal_load(&colcsr[pc]);
    const _Float16* Pp = P + (size_t)rx * C + lq * 8;
    const _Float16* Qp = Q + (size_t)ry * C + lq * 8;
#pragma unroll
    for (int kk = 0; kk < 4; ++kk) {
      half8v pa = *(const half8v*)(Pp + kk * 32);
      half8v qa = *(const half8v*)(Qp + kk * 32);
      half8v s = pa + qa;
#pragma unroll
      for (int j = 0; j < 8; ++j)
        s[j] = (s[j] > (_Float16)0.f) ? s[j] : (_Float16)0.f;
      a[tt][kk] = s;
    }
  }
  __syncthreads();  // waits for staging writes (and drains gathers)

  float4v acc[2][8];
#pragma unroll
  for (int tt = 0; tt < 2; ++tt)
#pragma unroll
    for (int j = 0; j < 8; ++j) acc[tt][j] = (float4v){0.f, 0.f, 0.f, 0.f};

#pragma unroll
  for (int kk = 0; kk < 4; ++kk) {
#pragma unroll
    for (int j = 0; j < 8; ++j) {
      half8v b = *(const half8v*)(WL + (((kk * 8 + j) * 64 + lane) << 3));
#pragma unroll
      for (int tt = 0; tt < 2; ++tt)
        acc[tt][j] = __builtin_amdgcn_mfma_f32_16x16x32_f16(a[tt][kk], b,
                                                            acc[tt][j], 0, 0, 0);
    }
  }

  // epilogue: second MLP layer + dot with w2, per tile
  float b1v[8], w2v[8];
#pragma unroll
  for (int j = 0; j < 8; ++j) {
    int n = j * 16 + lm;
    b1v[j] = b1[n];
    w2v[j] = w2[n];
  }
  float bb = b2[0];
#pragma unroll
  for (int tt = 0; tt < 2; ++tt) {
    float partv[4] = {0.f, 0.f, 0.f, 0.f};
#pragma unroll
    for (int j = 0; j < 8; ++j) {
#pragma unroll
      for (int r = 0; r < 4; ++r) {
        float e2 = fmaxf(acc[tt][j][r] + b1v[j], 0.f);
        partv[r] = fmaf(e2, w2v[j], partv[r]);
      }
    }
#pragma unroll
    for (int off = 1; off < 16; off <<= 1) {
#pragma unroll
      for (int r = 0; r < 4; ++r) partv[r] += __shfl_xor(partv[r], off, 64);
    }
    if (lm == 0) {
#pragma unroll
      for (int r = 0; r < 4; ++r) {
        int pe = base + tt * 16 + lq * 4 + r;
        if (pe < E) __builtin_nontemporal_store(partv[r] + bb, &tmpout[pe]);
      }
    }
  }
}

// ---------------- permute: out[e] = tmp[inv[e]] --------------------------
// tmp gather stays CACHED (each 64B tmp line is consumed ~16x); inv read
// and out write are streamed once -> non-temporal.
__global__ void k_perm(const float* __restrict__ tmp, const int* __restrict__ inv,
                       float* __restrict__ out, int E) {
  int e = blockIdx.x * 256 + threadIdx.x;
  if (e < E) {
    int idx = __builtin_nontemporal_load(&inv[e]);
    float v = tmp[idx];
    __builtin_nontemporal_store(v, &out[e]);
  }
}

// ---------------- host ---------------------------------------------------
extern "C" void kernel_launch(void* const* d_in, const int* in_sizes, int n_in,
                              void* d_out, int out_size, void* d_ws, size_t ws_size,
                              hipStream_t stream) {
  const float* x       = (const float*)d_in[0];
  const int*   ei      = (const int*)d_in[1];
  const float* convs_W = (const float*)d_in[2];
  const float* convs_b = (const float*)d_in[3];
  const float* fc0_W   = (const float*)d_in[4];
  const float* fc0_b   = (const float*)d_in[5];
  const float* fc1_W   = (const float*)d_in[6];
  const float* fc1_b   = (const float*)d_in[7];
  const float* fc2_W   = (const float*)d_in[8];
  const float* fc2_b   = (const float*)d_in[9];
  float* out = (float*)d_out;

  const int N = in_sizes[0] / C;        // 50000
  const int E = in_sizes[1] / 2;        // 1600000
  const int L = in_sizes[2] / (C * C);  // 8
  const int* row = ei;
  const int* col = ei + E;
  const int SB = (N + 255) / 256;       // 196 scan blocks (<=256)

  char* wp = (char*)d_ws;
  auto carve = [&](size_t bytes) {
    char* p = wp; wp += (bytes + 255) & ~(size_t)255; return p;
  };
  int*      cnt    = (int*)carve((size_t)N * 4);
  int*      part   = (int*)carve((size_t)SB * 4);
  int*      indptr = (int*)carve((size_t)(N + 1) * 4);
  int*      cursor = (int*)carve((size_t)N * 4);
  float*    dis    = (float*)carve((size_t)N * 4);
  int2*     emeta  = (int2*)carve((size_t)E * 8);
  int*      colcsr = (int*)carve((size_t)E * 4);
  int*      inv    = (int*)carve((size_t)E * 4);
  float*    tmpout = (float*)carve((size_t)E * 4);
  _Float16* Wf     = (_Float16*)carve((size_t)C * C * 2);
  _Float16* Wfh    = (_Float16*)carve((size_t)10 * C * C * 2);
  _Float16* Wfl    = (_Float16*)carve((size_t)10 * C * C * 2);
  _Float16* xh     = (_Float16*)carve((size_t)N * C * 2);
  _Float16* h0     = (_Float16*)carve((size_t)N * C * 2);
  _Float16* h1     = (_Float16*)carve((size_t)N * C * 2);
  _Float16* aggb   = (_Float16*)carve((size_t)N * C * 2);
  _Float16* Pm     = (_Float16*)carve((size_t)N * C * 2);
  _Float16* Qm     = (_Float16*)carve((size_t)N * C * 2);

  hipMemsetAsync(cnt, 0, (size_t)N * 4, stream);
  k_degree<<<(E + 255) / 256, 256, 0, stream>>>(col, cnt, E);
  k_scan_part<<<SB, 256, 0, stream>>>(cnt, part, N);
  k_scan_mid<<<1, 256, 0, stream>>>(part, SB);
  k_scan_fin<<<SB, 256, 0, stream>>>(cnt, part, dis, indptr, cursor, N);
  k_csrfill<<<(E + 255) / 256, 256, 0, stream>>>(row, col, dis, cursor,
                                                 emeta, inv, E);
  k_colfill<<<(N * 64 + 255) / 256, 256, 0, stream>>>(indptr, colcsr, N);
  k_prepwf<<<C * C / 256, 256, 0, stream>>>(fc1_W, Wf);
  k_prepw2<<<10 * C * C / 256, 256, 0, stream>>>(convs_W, fc0_W, Wfh, Wfl);
  k_cvt<<<(N * C / 4 + 255) / 256, 256, 0, stream>>>(x, xh, N * C / 4);

  int aggBlocks  = (N * 64 + 255) / 256;
  int gemmBlocks = (N + 63) / 64;
  const int MSZ = C * C;

  // layer 0 (no skip)
  k_agg<<<aggBlocks, 256, 0, stream>>>(xh, indptr, emeta, dis, aggb, N);
  k_gemm_f16<<<gemmBlocks, 256, 0, stream>>>(aggb, Wfh, Wfl, convs_b,
                                             nullptr, h0, N, 1);
  _Float16* hcur = h0; _Float16* hoth = h1;
  for (int l = 1; l < L; ++l) {
    k_agg<<<aggBlocks, 256, 0, stream>>>(hcur, indptr, emeta, dis, aggb, N);
    k_gemm_f16<<<gemmBlocks, 256, 0, stream>>>(aggb, Wfh + (size_t)l * MSZ,
                                               Wfl + (size_t)l * MSZ,
                                               convs_b + (size_t)l * C, hcur,
                                               hoth, N, 1);
    _Float16* tmp = hcur; hcur = hoth; hoth = tmp;
  }
  // edge MLP: P = h@fc0_W[:128], Q = h@fc0_W[128:] + b0
  k_gemm_f16<<<gemmBlocks, 256, 0, stream>>>(hcur, Wfh + (size_t)8 * MSZ,
                                             Wfl + (size_t)8 * MSZ, nullptr,
                                             nullptr, Pm, N, 0);
  k_gemm_f16<<<gemmBlocks, 256, 0, stream>>>(hcur, Wfh + (size_t)9 * MSZ,
                                             Wfl + (size_t)9 * MSZ, fc0_b,
                                             nullptr, Qm, N, 0);
  k_edge<<<(E + 127) / 128, 256, 0, stream>>>(Pm, Qm, emeta, colcsr, Wf, fc1_b,
                                              fc2_W, fc2_b, tmpout, E);
  k_perm<<<(E + 255) / 256, 256, 0, stream>>>(tmpout, inv, out, E);
}

// Round 5
// 1059.010 us; speedup vs baseline: 1.1452x; 1.1452x over previous
//
#include <hip/hip_runtime.h>

#define C 128

typedef __attribute__((ext_vector_type(4))) float float4v;
typedef _Float16 half8v __attribute__((ext_vector_type(8)));
typedef _Float16 half4v __attribute__((ext_vector_type(4)));

// ---------------- degree count ------------------------------------------
__global__ void k_degree(const int* __restrict__ col, int* __restrict__ cnt, int E) {
  int e = blockIdx.x * blockDim.x + threadIdx.x;
  if (e < E) atomicAdd(&cnt[col[e]], 1);
}

// ---------------- hierarchical scan (3 kernels, all wide) ---------------
__global__ void k_scan_part(const int* __restrict__ cnt, int* __restrict__ part,
                            int N) {
  __shared__ int sb[256];
  int t = threadIdx.x;
  int i = blockIdx.x * 256 + t;
  sb[t] = (i < N) ? cnt[i] : 0;
  __syncthreads();
#pragma unroll
  for (int off = 128; off > 0; off >>= 1) {
    if (t < off) sb[t] += sb[t + off];
    __syncthreads();
  }
  if (t == 0) part[blockIdx.x] = sb[0];
}

__global__ void k_scan_mid(int* __restrict__ part, int P) {
  __shared__ int sb[256];
  int t = threadIdx.x;
  int v = (t < P) ? part[t] : 0;
  sb[t] = v;
  __syncthreads();
#pragma unroll
  for (int off = 1; off < 256; off <<= 1) {
    int u = (t >= off) ? sb[t - off] : 0;
    __syncthreads();
    sb[t] += u;
    __syncthreads();
  }
  if (t < P) part[t] = sb[t] - v;  // exclusive
}

__global__ void k_scan_fin(const int* __restrict__ cnt, const int* __restrict__ part,
                           float* __restrict__ dis, int* __restrict__ indptr,
                           int* __restrict__ cursor, int N) {
  __shared__ int sb[256];
  int t = threadIdx.x;
  int i = blockIdx.x * 256 + t;
  int v = (i < N) ? cnt[i] : 0;
  sb[t] = v;
  __syncthreads();
#pragma unroll
  for (int off = 1; off < 256; off <<= 1) {
    int u = (t >= off) ? sb[t - off] : 0;
    __syncthreads();
    sb[t] += u;
    __syncthreads();
  }
  int run = part[blockIdx.x] + sb[t] - v;  // exclusive prefix
  if (i < N) {
    indptr[i] = run;
    cursor[i] = run;
    dis[i] = rsqrtf((float)(v + 1));  // +1 self loop
    if (i == N - 1) indptr[N] = run + v;
  }
}

// ---------------- CSR fill (dst-sorted) ---------------------------------
// v2: only emeta is scatter-written (epair removed; col id is regenerated
// by k_colfill as a coalesced segmented fill) -> halves the 64B-line
// write amplification that made this kernel write-bound.
__global__ void k_csrfill(const int* __restrict__ row, const int* __restrict__ col,
                          const float* __restrict__ dis, int* __restrict__ cursor,
                          int2* __restrict__ emeta, int* __restrict__ inv, int E) {
  int e = blockIdx.x * blockDim.x + threadIdx.x;
  if (e >= E) return;
  int r = row[e], c = col[e];
  int pos = atomicAdd(&cursor[c], 1);
  float nrm = dis[r] * dis[c];
  emeta[pos] = make_int2(r, __float_as_int(nrm));
  inv[e] = pos;
}

// ---------------- col-per-position fill (coalesced) ----------------------
// wave per node: colcsr[indptr[w]..indptr[w+1]) = w. Streaming writes.
__global__ void k_colfill(const int* __restrict__ indptr, int* __restrict__ colcsr,
                          int N) {
  int w = (blockIdx.x * 256 + threadIdx.x) >> 6;
  int lane = threadIdx.x & 63;
  if (w >= N) return;
  int s = indptr[w], e = indptr[w + 1];
  for (int i = s + lane; i < e; i += 64) colcsr[i] = w;
}

// ---------------- x fp32 -> fp16 ----------------------------------------
__global__ void k_cvt(const float* __restrict__ x, _Float16* __restrict__ xh, int n4) {
  int i = blockIdx.x * 256 + threadIdx.x;
  if (i >= n4) return;
  float4 v = ((const float4*)x)[i];
  half4v o = {(_Float16)v.x, (_Float16)v.y, (_Float16)v.z, (_Float16)v.w};
  *(half4v*)(xh + i * 4) = o;
}

// ---------------- W1 -> fp16 fragment-major table (fc1) ------------------
__global__ void k_prepwf(const float* __restrict__ W1, _Float16* __restrict__ Wf) {
  int idx = blockIdx.x * 256 + threadIdx.x;  // 16384
  int e = idx & 7, lane = (idx >> 3) & 63, j = (idx >> 9) & 7, kk = idx >> 12;
  int n = j * 16 + (lane & 15);
  int k = (kk * 4 + (lane >> 4)) * 8 + e;
  Wf[idx] = (_Float16)W1[k * C + n];
}

// ------- conv/fc0 W -> fragment-major fp16 hi + scaled-lo (10 mats) ------
// lo = fp16((W - hi) * 4096) keeps residual normal; epilogue recombines
// acc_h + acc_l/4096 -> fp32-equivalent W.
__global__ void k_prepw2(const float* __restrict__ convs_W,
                         const float* __restrict__ fc0_W,
                         _Float16* __restrict__ Wfh, _Float16* __restrict__ Wfl) {
  int g = blockIdx.x * 256 + threadIdx.x;  // [0, 10*16384)
  int mat = g >> 14, idx = g & 16383;
  int e = idx & 7, lane = (idx >> 3) & 63, j = (idx >> 9) & 7, kk = idx >> 12;
  int n = j * 16 + (lane & 15);
  int k = (kk * 4 + (lane >> 4)) * 8 + e;
  const float* src = (mat < 8) ? convs_W + ((size_t)mat << 14)
                               : fc0_W + ((size_t)(mat - 8) << 14);
  float v = src[k * C + n];
  _Float16 h = (_Float16)v;
  Wfh[g] = h;
  Wfl[g] = (_Float16)((v - (float)h) * 4096.f);
}

// ---------------- aggregation (fp16 h -> fp16 agg) -----------------------
// Wave per node (round-3 proven body: no register cap -- forcing <=64 VGPR
// in round 4 cost ~25us/dispatch by strangling gather MLP). emeta loads
// software-pipelined one 16-edge chunk ahead; self-row/dis hoisted to top;
// emeta non-temporal (streamed once).
__global__ __launch_bounds__(256)
void k_agg(const _Float16* __restrict__ h, const int* __restrict__ indptr,
           const int2* __restrict__ emeta, const float* __restrict__ dis,
           _Float16* __restrict__ agg, int N) {
  int w = (blockIdx.x * 256 + threadIdx.x) >> 6;
  int lane = threadIdx.x & 63;
  if (w >= N) return;
  int g16 = lane >> 4, c8 = lane & 15;
  int s = indptr[w], e = indptr[w + 1];

  // hoist self-term loads (used only at the end; issue early)
  float dv = 0.f;
  half8v hs = {};
  if (lane < 16) {
    dv = dis[w];
    hs = *(const half8v*)(h + (size_t)w * C + lane * 8);
  }

  float acc[8];
#pragma unroll
  for (int j = 0; j < 8; ++j) acc[j] = 0.f;

  int i = s;
  long long mc[4];
  if (i + 16 <= e) {
#pragma unroll
    for (int u = 0; u < 4; ++u)
      mc[u] = __builtin_nontemporal_load(
          (const long long*)&emeta[i + u * 4 + g16]);
  }
  for (; i + 16 <= e;) {
    int inext = i + 16;
    bool hn = (inext + 16 <= e);
    long long mn[4];
    if (hn) {
#pragma unroll
      for (int u = 0; u < 4; ++u)
        mn[u] = __builtin_nontemporal_load(
            (const long long*)&emeta[inext + u * 4 + g16]);
    }
    half8v hv[4];
#pragma unroll
    for (int u = 0; u < 4; ++u) {
      int srcn = (int)(mc[u] & 0xffffffffLL);
      hv[u] = *(const half8v*)(h + (size_t)srcn * C + c8 * 8);
    }
#pragma unroll
    for (int u = 0; u < 4; ++u) {
      float nn = __int_as_float((int)(mc[u] >> 32));
#pragma unroll
      for (int j = 0; j < 8; ++j) acc[j] += nn * (float)hv[u][j];
    }
    if (hn) {
#pragma unroll
      for (int u = 0; u < 4; ++u) mc[u] = mn[u];
    }
    i = inext;
  }
  for (; i + 4 <= e; i += 4) {
    long long m = __builtin_nontemporal_load((const long long*)&emeta[i + g16]);
    int srcn = (int)(m & 0xffffffffLL);
    half8v hv = *(const half8v*)(h + (size_t)srcn * C + c8 * 8);
    float nn = __int_as_float((int)(m >> 32));
#pragma unroll
    for (int j = 0; j < 8; ++j) acc[j] += nn * (float)hv[j];
  }
  if (i < e) {  // tail 1..3: out-of-range lanes use norm 0
    int idx = i + g16;
    int srcn = w;
    float nn = 0.f;
    if (idx < e) {
      long long m = __builtin_nontemporal_load((const long long*)&emeta[idx]);
      srcn = (int)(m & 0xffffffffLL);
      nn = __int_as_float((int)(m >> 32));
    }
    half8v hv = *(const half8v*)(h + (size_t)srcn * C + c8 * 8);
#pragma unroll
    for (int j = 0; j < 8; ++j) acc[j] += nn * (float)hv[j];
  }
#pragma unroll
  for (int j = 0; j < 8; ++j) {
    acc[j] += __shfl_xor(acc[j], 16, 64);
    acc[j] += __shfl_xor(acc[j], 32, 64);
  }
  if (lane < 16) {
    float dv2 = dv * dv;
    half8v o;
#pragma unroll
    for (int j = 0; j < 8; ++j) o[j] = (_Float16)(acc[j] + dv2 * (float)hs[j]);
    *(half8v*)(agg + (size_t)w * C + lane * 8) = o;
  }
}

// ---------------- streaming f16 MFMA GEMM (no LDS, no barrier) ----------
__global__ __launch_bounds__(256, 4)
void k_gemm_f16(const _Float16* __restrict__ A,
                const _Float16* __restrict__ Wfh, const _Float16* __restrict__ Wfl,
                const float* __restrict__ bias, const _Float16* __restrict__ skip,
                _Float16* __restrict__ out, int M, int relu) {
  int t = threadIdx.x;
  int r0 = blockIdx.x * 64;
  int w = t >> 6, lane = t & 63;
  int m0 = w * 16, lm = lane & 15, lq = lane >> 4;
  int row = r0 + m0 + lm;
  if (row >= M) row = M - 1;
  const _Float16* Ar = A + (size_t)row * C;

  float4v acch[8], accl[8];
#pragma unroll
  for (int j = 0; j < 8; ++j) {
    acch[j] = (float4v){0.f, 0.f, 0.f, 0.f};
    accl[j] = (float4v){0.f, 0.f, 0.f, 0.f};
  }
#pragma unroll
  for (int kk = 0; kk < 4; ++kk) {
    half8v a = *(const half8v*)(Ar + kk * 32 + lq * 8);
#pragma unroll
    for (int j = 0; j < 8; ++j) {
      int fi = ((kk * 8 + j) * 64 + lane) << 3;
      half8v bh = *(const half8v*)(Wfh + fi);
      half8v bl = *(const half8v*)(Wfl + fi);
      acch[j] = __builtin_amdgcn_mfma_f32_16x16x32_f16(a, bh, acch[j], 0, 0, 0);
      accl[j] = __builtin_amdgcn_mfma_f32_16x16x32_f16(a, bl, accl[j], 0, 0, 0);
    }
  }
#pragma unroll
  for (int j = 0; j < 8; ++j) {
    int n = j * 16 + lm;
    float bv = bias ? bias[n] : 0.f;
#pragma unroll
    for (int r = 0; r < 4; ++r) {
      int m = r0 + m0 + lq * 4 + r;
      if (m >= M) continue;
      float v = acch[j][r] + accl[j][r] * (1.f / 4096.f) + bv;
      if (skip) v += (float)skip[(size_t)m * C + n];
      if (relu) v = fmaxf(v, 0.f);
      out[(size_t)m * C + n] = (_Float16)v;
    }
  }
}

// ---------------- fused edge MLP (fp16, CSR order, LDS weights) ----------
// fc1 fragment table (32KB) staged once per block in LDS; 32 edges/wave;
// (r,c) come from emeta.x (already scatter-written for agg) + colcsr
// (coalesced segmented fill) -- epair array eliminated.
__global__ __launch_bounds__(256, 4)
void k_edge(const _Float16* __restrict__ P, const _Float16* __restrict__ Q,
            const int2* __restrict__ emeta, const int* __restrict__ colcsr,
            const _Float16* __restrict__ Wf,
            const float* __restrict__ b1, const float* __restrict__ w2,
            const float* __restrict__ b2, float* __restrict__ tmpout, int E) {
  __shared__ __align__(16) _Float16 WL[16384];
  int t = threadIdx.x;
#pragma unroll
  for (int it = 0; it < 8; ++it) {
    int off = it * 2048 + t * 8;  // 4KB per iter, lane-major: conflict-free
    *(half8v*)(WL + off) = *(const half8v*)(Wf + off);
  }

  int w = t >> 6, lane = t & 63;
  int lm = lane & 15, lq = lane >> 4;
  int base = blockIdx.x * 128 + w * 32;  // wave's 32-edge range

  // gather + fuse: a[tile][kk] = relu(P[src]+Q[dst]) fragments
  half8v a[2][4];
#pragma unroll
  for (int tt = 0; tt < 2; ++tt) {
    int p = base + tt * 16 + lm;
    int pc = (p < E) ? p : (E - 1);
    long long ev = __builtin_nontemporal_load((const long long*)&emeta[pc]);
    int rx = (int)(ev & 0xffffffffLL);
    int ry = __builtin_nontemporal_load(&colcsr[pc]);
    const _Float16* Pp = P + (size_t)rx * C + lq * 8;
    const _Float16* Qp = Q + (size_t)ry * C + lq * 8;
#pragma unroll
    for (int kk = 0; kk < 4; ++kk) {
      half8v pa = *(const half8v*)(Pp + kk * 32);
      half8v qa = *(const half8v*)(Qp + kk * 32);
      half8v s = pa + qa;
#pragma unroll
      for (int j = 0; j < 8; ++j)
        s[j] = (s[j] > (_Float16)0.f) ? s[j] : (_Float16)0.f;
      a[tt][kk] = s;
    }
  }
  __syncthreads();  // waits for staging writes (and drains gathers)

  float4v acc[2][8];
#pragma unroll
  for (int tt = 0; tt < 2; ++tt)
#pragma unroll
    for (int j = 0; j < 8; ++j) acc[tt][j] = (float4v){0.f, 0.f, 0.f, 0.f};

#pragma unroll
  for (int kk = 0; kk < 4; ++kk) {
#pragma unroll
    for (int j = 0; j < 8; ++j) {
      half8v b = *(const half8v*)(WL + (((kk * 8 + j) * 64 + lane) << 3));
#pragma unroll
      for (int tt = 0; tt < 2; ++tt)
        acc[tt][j] = __builtin_amdgcn_mfma_f32_16x16x32_f16(a[tt][kk], b,
                                                            acc[tt][j], 0, 0, 0);
    }
  }

  // epilogue: second MLP layer + dot with w2, per tile
  float b1v[8], w2v[8];
#pragma unroll
  for (int j = 0; j < 8; ++j) {
    int n = j * 16 + lm;
    b1v[j] = b1[n];
    w2v[j] = w2[n];
  }
  float bb = b2[0];
#pragma unroll
  for (int tt = 0; tt < 2; ++tt) {
    float partv[4] = {0.f, 0.f, 0.f, 0.f};
#pragma unroll
    for (int j = 0; j < 8; ++j) {
#pragma unroll
      for (int r = 0; r < 4; ++r) {
        float e2 = fmaxf(acc[tt][j][r] + b1v[j], 0.f);
        partv[r] = fmaf(e2, w2v[j], partv[r]);
      }
    }
#pragma unroll
    for (int off = 1; off < 16; off <<= 1) {
#pragma unroll
      for (int r = 0; r < 4; ++r) partv[r] += __shfl_xor(partv[r], off, 64);
    }
    if (lm == 0) {
#pragma unroll
      for (int r = 0; r < 4; ++r) {
        int pe = base + tt * 16 + lq * 4 + r;
        if (pe < E) __builtin_nontemporal_store(partv[r] + bb, &tmpout[pe]);
      }
    }
  }
}

// ---------------- permute: out[e] = tmp[inv[e]] --------------------------
// tmp gather stays CACHED (each 64B tmp line is consumed ~16x); inv read
// and out write are streamed once -> non-temporal.
__global__ void k_perm(const float* __restrict__ tmp, const int* __restrict__ inv,
                       float* __restrict__ out, int E) {
  int e = blockIdx.x * 256 + threadIdx.x;
  if (e < E) {
    int idx = __builtin_nontemporal_load(&inv[e]);
    float v = tmp[idx];
    __builtin_nontemporal_store(v, &out[e]);
  }
}

// ---------------- host ---------------------------------------------------
extern "C" void kernel_launch(void* const* d_in, const int* in_sizes, int n_in,
                              void* d_out, int out_size, void* d_ws, size_t ws_size,
                              hipStream_t stream) {
  const float* x       = (const float*)d_in[0];
  const int*   ei      = (const int*)d_in[1];
  const float* convs_W = (const float*)d_in[2];
  const float* convs_b = (const float*)d_in[3];
  const float* fc0_W   = (const float*)d_in[4];
  const float* fc0_b   = (const float*)d_in[5];
  const float* fc1_W   = (const float*)d_in[6];
  const float* fc1_b   = (const float*)d_in[7];
  const float* fc2_W   = (const float*)d_in[8];
  const float* fc2_b   = (const float*)d_in[9];
  float* out = (float*)d_out;

  const int N = in_sizes[0] / C;        // 50000
  const int E = in_sizes[1] / 2;        // 1600000
  const int L = in_sizes[2] / (C * C);  // 8
  const int* row = ei;
  const int* col = ei + E;
  const int SB = (N + 255) / 256;       // 196 scan blocks (<=256)

  char* wp = (char*)d_ws;
  auto carve = [&](size_t bytes) {
    char* p = wp; wp += (bytes + 255) & ~(size_t)255; return p;
  };
  int*      cnt    = (int*)carve((size_t)N * 4);
  int*      part   = (int*)carve((size_t)SB * 4);
  int*      indptr = (int*)carve((size_t)(N + 1) * 4);
  int*      cursor = (int*)carve((size_t)N * 4);
  float*    dis    = (float*)carve((size_t)N * 4);
  int2*     emeta  = (int2*)carve((size_t)E * 8);
  int*      colcsr = (int*)carve((size_t)E * 4);
  int*      inv    = (int*)carve((size_t)E * 4);
  float*    tmpout = (float*)carve((size_t)E * 4);
  _Float16* Wf     = (_Float16*)carve((size_t)C * C * 2);
  _Float16* Wfh    = (_Float16*)carve((size_t)10 * C * C * 2);
  _Float16* Wfl    = (_Float16*)carve((size_t)10 * C * C * 2);
  _Float16* xh     = (_Float16*)carve((size_t)N * C * 2);
  _Float16* h0     = (_Float16*)carve((size_t)N * C * 2);
  _Float16* h1     = (_Float16*)carve((size_t)N * C * 2);
  _Float16* aggb   = (_Float16*)carve((size_t)N * C * 2);
  _Float16* Pm     = (_Float16*)carve((size_t)N * C * 2);
  _Float16* Qm     = (_Float16*)carve((size_t)N * C * 2);

  hipMemsetAsync(cnt, 0, (size_t)N * 4, stream);
  k_degree<<<(E + 255) / 256, 256, 0, stream>>>(col, cnt, E);
  k_scan_part<<<SB, 256, 0, stream>>>(cnt, part, N);
  k_scan_mid<<<1, 256, 0, stream>>>(part, SB);
  k_scan_fin<<<SB, 256, 0, stream>>>(cnt, part, dis, indptr, cursor, N);
  k_csrfill<<<(E + 255) / 256, 256, 0, stream>>>(row, col, dis, cursor,
                                                 emeta, inv, E);
  k_colfill<<<(N * 64 + 255) / 256, 256, 0, stream>>>(indptr, colcsr, N);
  k_prepwf<<<C * C / 256, 256, 0, stream>>>(fc1_W, Wf);
  k_prepw2<<<10 * C * C / 256, 256, 0, stream>>>(convs_W, fc0_W, Wfh, Wfl);
  k_cvt<<<(N * C / 4 + 255) / 256, 256, 0, stream>>>(x, xh, N * C / 4);

  int aggBlocks  = (N * 64 + 255) / 256;
  int gemmBlocks = (N + 63) / 64;
  const int MSZ = C * C;

  // layer 0 (no skip)
  k_agg<<<aggBlocks, 256, 0, stream>>>(xh, indptr, emeta, dis, aggb, N);
  k_gemm_f16<<<gemmBlocks, 256, 0, stream>>>(aggb, Wfh, Wfl, convs_b,
                                             nullptr, h0, N, 1);
  _Float16* hcur = h0; _Float16* hoth = h1;
  for (int l = 1; l < L; ++l) {
    k_agg<<<aggBlocks, 256, 0, stream>>>(hcur, indptr, emeta, dis, aggb, N);
    k_gemm_f16<<<gemmBlocks, 256, 0, stream>>>(aggb, Wfh + (size_t)l * MSZ,
                                               Wfl + (size_t)l * MSZ,
                                               convs_b + (size_t)l * C, hcur,
                                               hoth, N, 1);
    _Float16* tmp = hcur; hcur = hoth; hoth = tmp;
  }
  // edge MLP: P = h@fc0_W[:128], Q = h@fc0_W[128:] + b0
  k_gemm_f16<<<gemmBlocks, 256, 0, stream>>>(hcur, Wfh + (size_t)8 * MSZ,
                                             Wfl + (size_t)8 * MSZ, nullptr,
                                             nullptr, Pm, N, 0);
  k_gemm_f16<<<gemmBlocks, 256, 0, stream>>>(hcur, Wfh + (size_t)9 * MSZ,
                                             Wfl + (size_t)9 * MSZ, fc0_b,
                                             nullptr, Qm, N, 0);
  k_edge<<<(E + 127) / 128, 256, 0, stream>>>(Pm, Qm, emeta, colcsr, Wf, fc1_b,
                                              fc2_W, fc2_b, tmpout, E);
  k_perm<<<(E + 255) / 256, 256, 0, stream>>>(tmpout, inv, out, E);
}

// Round 6
// 1057.482 us; speedup vs baseline: 1.1469x; 1.0014x over previous
//
#include <hip/hip_runtime.h>

#define C 128

typedef __attribute__((ext_vector_type(4))) float float4v;
typedef _Float16 half8v __attribute__((ext_vector_type(8)));
typedef _Float16 half4v __attribute__((ext_vector_type(4)));

// ---------------- degree count ------------------------------------------
__global__ void k_degree(const int* __restrict__ col, int* __restrict__ cnt, int E) {
  int e = blockIdx.x * blockDim.x + threadIdx.x;
  if (e < E) atomicAdd(&cnt[col[e]], 1);
}

// ---------------- hierarchical scan (3 kernels, all wide) ---------------
__global__ void k_scan_part(const int* __restrict__ cnt, int* __restrict__ part,
                            int N) {
  __shared__ int sb[256];
  int t = threadIdx.x;
  int i = blockIdx.x * 256 + t;
  sb[t] = (i < N) ? cnt[i] : 0;
  __syncthreads();
#pragma unroll
  for (int off = 128; off > 0; off >>= 1) {
    if (t < off) sb[t] += sb[t + off];
    __syncthreads();
  }
  if (t == 0) part[blockIdx.x] = sb[0];
}

__global__ void k_scan_mid(int* __restrict__ part, int P) {
  __shared__ int sb[256];
  int t = threadIdx.x;
  int v = (t < P) ? part[t] : 0;
  sb[t] = v;
  __syncthreads();
#pragma unroll
  for (int off = 1; off < 256; off <<= 1) {
    int u = (t >= off) ? sb[t - off] : 0;
    __syncthreads();
    sb[t] += u;
    __syncthreads();
  }
  if (t < P) part[t] = sb[t] - v;  // exclusive
}

__global__ void k_scan_fin(const int* __restrict__ cnt, const int* __restrict__ part,
                           float* __restrict__ dis, int* __restrict__ indptr,
                           int* __restrict__ cursor, int N) {
  __shared__ int sb[256];
  int t = threadIdx.x;
  int i = blockIdx.x * 256 + t;
  int v = (i < N) ? cnt[i] : 0;
  sb[t] = v;
  __syncthreads();
#pragma unroll
  for (int off = 1; off < 256; off <<= 1) {
    int u = (t >= off) ? sb[t - off] : 0;
    __syncthreads();
    sb[t] += u;
    __syncthreads();
  }
  int run = part[blockIdx.x] + sb[t] - v;  // exclusive prefix
  if (i < N) {
    indptr[i] = run;
    cursor[i] = run;
    dis[i] = rsqrtf((float)(v + 1));  // +1 self loop
    if (i == N - 1) indptr[N] = run + v;
  }
}

// ---------------- CSR fill (dst-sorted) ---------------------------------
// only emeta is scatter-written (epair removed; col id regenerated by
// k_colfill as a coalesced segmented fill).
__global__ void k_csrfill(const int* __restrict__ row, const int* __restrict__ col,
                          const float* __restrict__ dis, int* __restrict__ cursor,
                          int2* __restrict__ emeta, int* __restrict__ inv, int E) {
  int e = blockIdx.x * blockDim.x + threadIdx.x;
  if (e >= E) return;
  int r = row[e], c = col[e];
  int pos = atomicAdd(&cursor[c], 1);
  float nrm = dis[r] * dis[c];
  emeta[pos] = make_int2(r, __float_as_int(nrm));
  inv[e] = pos;
}

// ---------------- col-per-position fill (coalesced) ----------------------
__global__ void k_colfill(const int* __restrict__ indptr, int* __restrict__ colcsr,
                          int N) {
  int w = (blockIdx.x * 256 + threadIdx.x) >> 6;
  int lane = threadIdx.x & 63;
  if (w >= N) return;
  int s = indptr[w], e = indptr[w + 1];
  for (int i = s + lane; i < e; i += 64) colcsr[i] = w;
}

// ---------------- x fp32 -> fp16 ----------------------------------------
__global__ void k_cvt(const float* __restrict__ x, _Float16* __restrict__ xh, int n4) {
  int i = blockIdx.x * 256 + threadIdx.x;
  if (i >= n4) return;
  float4 v = ((const float4*)x)[i];
  half4v o = {(_Float16)v.x, (_Float16)v.y, (_Float16)v.z, (_Float16)v.w};
  *(half4v*)(xh + i * 4) = o;
}

// ---------------- W1 -> fp16 fragment-major table (fc1) ------------------
__global__ void k_prepwf(const float* __restrict__ W1, _Float16* __restrict__ Wf) {
  int idx = blockIdx.x * 256 + threadIdx.x;  // 16384
  int e = idx & 7, lane = (idx >> 3) & 63, j = (idx >> 9) & 7, kk = idx >> 12;
  int n = j * 16 + (lane & 15);
  int k = (kk * 4 + (lane >> 4)) * 8 + e;
  Wf[idx] = (_Float16)W1[k * C + n];
}

// ------- conv/fc0 W -> fragment-major fp16 hi + scaled-lo (10 mats) ------
__global__ void k_prepw2(const float* __restrict__ convs_W,
                         const float* __restrict__ fc0_W,
                         _Float16* __restrict__ Wfh, _Float16* __restrict__ Wfl) {
  int g = blockIdx.x * 256 + threadIdx.x;  // [0, 10*16384)
  int mat = g >> 14, idx = g & 16383;
  int e = idx & 7, lane = (idx >> 3) & 63, j = (idx >> 9) & 7, kk = idx >> 12;
  int n = j * 16 + (lane & 15);
  int k = (kk * 4 + (lane >> 4)) * 8 + e;
  const float* src = (mat < 8) ? convs_W + ((size_t)mat << 14)
                               : fc0_W + ((size_t)(mat - 8) << 14);
  float v = src[k * C + n];
  _Float16 h = (_Float16)v;
  Wfh[g] = h;
  Wfl[g] = (_Float16)((v - (float)h) * 4096.f);
}

// ---------------- aggregation (fp16 h -> fp16 agg) -----------------------
// Wave per node. v4: (a) emeta loaded COALESCED (one 256B load per 32
// edges, entries distributed in-register via __shfl) instead of 8
// broadcast loads that wasted 15/16 of each VMEM slot; (b) 32-edge main
// chunks keep 8 row-gathers in flight (2x round-3's MLP). 16/4/tail
// fallthrough for the sub-32 remainder. No VGPR cap (round-4 lesson).
__global__ __launch_bounds__(256)
void k_agg(const _Float16* __restrict__ h, const int* __restrict__ indptr,
           const int2* __restrict__ emeta, const float* __restrict__ dis,
           _Float16* __restrict__ agg, int N) {
  int w = (blockIdx.x * 256 + threadIdx.x) >> 6;
  int lane = threadIdx.x & 63;
  if (w >= N) return;
  int g16 = lane >> 4, c8 = lane & 15;
  int s = indptr[w], e = indptr[w + 1];

  // hoist self-term loads (used only at the end; issue early)
  float dv = 0.f;
  half8v hs = {};
  if (lane < 16) {
    dv = dis[w];
    hs = *(const half8v*)(h + (size_t)w * C + lane * 8);
  }

  float acc[8];
#pragma unroll
  for (int j = 0; j < 8; ++j) acc[j] = 0.f;

  int i = s;
  // ---- 32-edge main loop: coalesced emeta + shfl bcast, 8 gathers deep
  if (i + 32 <= e) {
    long long mm = __builtin_nontemporal_load(
        (const long long*)&emeta[i + (lane & 31)]);
    for (;;) {
      int inext = i + 32;
      bool hn = (inext + 32 <= e);
      long long mmn = 0;
      if (hn)
        mmn = __builtin_nontemporal_load(
            (const long long*)&emeta[inext + (lane & 31)]);
      long long mu[8];
#pragma unroll
      for (int u = 0; u < 8; ++u) mu[u] = __shfl(mm, u * 4 + g16, 64);
      half8v hv[8];
#pragma unroll
      for (int u = 0; u < 8; ++u) {
        int srcn = (int)(mu[u] & 0xffffffffLL);
        hv[u] = *(const half8v*)(h + (size_t)srcn * C + c8 * 8);
      }
#pragma unroll
      for (int u = 0; u < 8; ++u) {
        float nn = __int_as_float((int)(mu[u] >> 32));
#pragma unroll
        for (int j = 0; j < 8; ++j) acc[j] += nn * (float)hv[u][j];
      }
      i = inext;
      if (!hn) break;
      mm = mmn;
    }
  }
  // ---- single 16-edge pass (direct loads)
  if (i + 16 <= e) {
    long long mc[4];
#pragma unroll
    for (int u = 0; u < 4; ++u)
      mc[u] = __builtin_nontemporal_load(
          (const long long*)&emeta[i + u * 4 + g16]);
    half8v hv[4];
#pragma unroll
    for (int u = 0; u < 4; ++u) {
      int srcn = (int)(mc[u] & 0xffffffffLL);
      hv[u] = *(const half8v*)(h + (size_t)srcn * C + c8 * 8);
    }
#pragma unroll
    for (int u = 0; u < 4; ++u) {
      float nn = __int_as_float((int)(mc[u] >> 32));
#pragma unroll
      for (int j = 0; j < 8; ++j) acc[j] += nn * (float)hv[u][j];
    }
    i += 16;
  }
  // ---- 4-edge loop
  for (; i + 4 <= e; i += 4) {
    long long m = __builtin_nontemporal_load((const long long*)&emeta[i + g16]);
    int srcn = (int)(m & 0xffffffffLL);
    half8v hv = *(const half8v*)(h + (size_t)srcn * C + c8 * 8);
    float nn = __int_as_float((int)(m >> 32));
#pragma unroll
    for (int j = 0; j < 8; ++j) acc[j] += nn * (float)hv[j];
  }
  if (i < e) {  // tail 1..3: out-of-range lanes use norm 0
    int idx = i + g16;
    int srcn = w;
    float nn = 0.f;
    if (idx < e) {
      long long m = __builtin_nontemporal_load((const long long*)&emeta[idx]);
      srcn = (int)(m & 0xffffffffLL);
      nn = __int_as_float((int)(m >> 32));
    }
    half8v hv = *(const half8v*)(h + (size_t)srcn * C + c8 * 8);
#pragma unroll
    for (int j = 0; j < 8; ++j) acc[j] += nn * (float)hv[j];
  }
#pragma unroll
  for (int j = 0; j < 8; ++j) {
    acc[j] += __shfl_xor(acc[j], 16, 64);
    acc[j] += __shfl_xor(acc[j], 32, 64);
  }
  if (lane < 16) {
    float dv2 = dv * dv;
    half8v o;
#pragma unroll
    for (int j = 0; j < 8; ++j) o[j] = (_Float16)(acc[j] + dv2 * (float)hs[j]);
    *(half8v*)(agg + (size_t)w * C + lane * 8) = o;
  }
}

// ---------------- streaming f16 MFMA GEMM (no LDS, no barrier) ----------
__global__ __launch_bounds__(256, 4)
void k_gemm_f16(const _Float16* __restrict__ A,
                const _Float16* __restrict__ Wfh, const _Float16* __restrict__ Wfl,
                const float* __restrict__ bias, const _Float16* __restrict__ skip,
                _Float16* __restrict__ out, int M, int relu) {
  int t = threadIdx.x;
  int r0 = blockIdx.x * 64;
  int w = t >> 6, lane = t & 63;
  int m0 = w * 16, lm = lane & 15, lq = lane >> 4;
  int row = r0 + m0 + lm;
  if (row >= M) row = M - 1;
  const _Float16* Ar = A + (size_t)row * C;

  float4v acch[8], accl[8];
#pragma unroll
  for (int j = 0; j < 8; ++j) {
    acch[j] = (float4v){0.f, 0.f, 0.f, 0.f};
    accl[j] = (float4v){0.f, 0.f, 0.f, 0.f};
  }
#pragma unroll
  for (int kk = 0; kk < 4; ++kk) {
    half8v a = *(const half8v*)(Ar + kk * 32 + lq * 8);
#pragma unroll
    for (int j = 0; j < 8; ++j) {
      int fi = ((kk * 8 + j) * 64 + lane) << 3;
      half8v bh = *(const half8v*)(Wfh + fi);
      half8v bl = *(const half8v*)(Wfl + fi);
      acch[j] = __builtin_amdgcn_mfma_f32_16x16x32_f16(a, bh, acch[j], 0, 0, 0);
      accl[j] = __builtin_amdgcn_mfma_f32_16x16x32_f16(a, bl, accl[j], 0, 0, 0);
    }
  }
#pragma unroll
  for (int j = 0; j < 8; ++j) {
    int n = j * 16 + lm;
    float bv = bias ? bias[n] : 0.f;
#pragma unroll
    for (int r = 0; r < 4; ++r) {
      int m = r0 + m0 + lq * 4 + r;
      if (m >= M) continue;
      float v = acch[j][r] + accl[j][r] * (1.f / 4096.f) + bv;
      if (skip) v += (float)skip[(size_t)m * C + n];
      if (relu) v = fmaxf(v, 0.f);
      out[(size_t)m * C + n] = (_Float16)v;
    }
  }
}

// ---------------- fc0 double GEMM: P and Q in one pass -------------------
// A-fragments loaded once into regs; two sequential acc passes over the
// mat-8 (P, no bias) and mat-9 (Q, +b0) weight tables. Halves A traffic
// and saves one dispatch vs two k_gemm_f16 calls.
__global__ __launch_bounds__(256, 4)
void k_gemm_fc0(const _Float16* __restrict__ A,
                const _Float16* __restrict__ Wfh, const _Float16* __restrict__ Wfl,
                const float* __restrict__ b0,
                _Float16* __restrict__ Pm, _Float16* __restrict__ Qm, int M) {
  int t = threadIdx.x;
  int r0 = blockIdx.x * 64;
  int w = t >> 6, lane = t & 63;
  int m0 = w * 16, lm = lane & 15, lq = lane >> 4;
  int row = r0 + m0 + lm;
  if (row >= M) row = M - 1;
  const _Float16* Ar = A + (size_t)row * C;
  half8v a[4];
#pragma unroll
  for (int kk = 0; kk < 4; ++kk) a[kk] = *(const half8v*)(Ar + kk * 32 + lq * 8);

#pragma unroll
  for (int half = 0; half < 2; ++half) {
    const _Float16* Bh = Wfh + half * (C * C);
    const _Float16* Bl = Wfl + half * (C * C);
    float4v acch[8], accl[8];
#pragma unroll
    for (int j = 0; j < 8; ++j) {
      acch[j] = (float4v){0.f, 0.f, 0.f, 0.f};
      accl[j] = (float4v){0.f, 0.f, 0.f, 0.f};
    }
#pragma unroll
    for (int kk = 0; kk < 4; ++kk) {
#pragma unroll
      for (int j = 0; j < 8; ++j) {
        int fi = ((kk * 8 + j) * 64 + lane) << 3;
        half8v bh = *(const half8v*)(Bh + fi);
        half8v bl = *(const half8v*)(Bl + fi);
        acch[j] = __builtin_amdgcn_mfma_f32_16x16x32_f16(a[kk], bh, acch[j], 0, 0, 0);
        accl[j] = __builtin_amdgcn_mfma_f32_16x16x32_f16(a[kk], bl, accl[j], 0, 0, 0);
      }
    }
    _Float16* outp = half ? Qm : Pm;
#pragma unroll
    for (int j = 0; j < 8; ++j) {
      int n = j * 16 + lm;
      float bv = half ? b0[n] : 0.f;
#pragma unroll
      for (int r = 0; r < 4; ++r) {
        int m = r0 + m0 + lq * 4 + r;
        if (m >= M) continue;
        float v = acch[j][r] + accl[j][r] * (1.f / 4096.f) + bv;
        outp[(size_t)m * C + n] = (_Float16)v;
      }
    }
  }
}

// ---------------- fused edge MLP (fp16, CSR order, LDS weights) ----------
__global__ __launch_bounds__(256, 4)
void k_edge(const _Float16* __restrict__ P, const _Float16* __restrict__ Q,
            const int2* __restrict__ emeta, const int* __restrict__ colcsr,
            const _Float16* __restrict__ Wf,
            const float* __restrict__ b1, const float* __restrict__ w2,
            const float* __restrict__ b2, float* __restrict__ tmpout, int E) {
  __shared__ __align__(16) _Float16 WL[16384];
  int t = threadIdx.x;
#pragma unroll
  for (int it = 0; it < 8; ++it) {
    int off = it * 2048 + t * 8;  // 4KB per iter, lane-major: conflict-free
    *(half8v*)(WL + off) = *(const half8v*)(Wf + off);
  }

  int w = t >> 6, lane = t & 63;
  int lm = lane & 15, lq = lane >> 4;
  int base = blockIdx.x * 128 + w * 32;  // wave's 32-edge range

  // gather + fuse: a[tile][kk] = relu(P[src]+Q[dst]) fragments
  half8v a[2][4];
#pragma unroll
  for (int tt = 0; tt < 2; ++tt) {
    int p = base + tt * 16 + lm;
    int pc = (p < E) ? p : (E - 1);
    long long ev = __builtin_nontemporal_load((const long long*)&emeta[pc]);
    int rx = (int)(ev & 0xffffffffLL);
    int ry = __builtin_nontemporal_load(&colcsr[pc]);
    const _Float16* Pp = P + (size_t)rx * C + lq * 8;
    const _Float16* Qp = Q + (size_t)ry * C + lq * 8;
#pragma unroll
    for (int kk = 0; kk < 4; ++kk) {
      half8v pa = *(const half8v*)(Pp + kk * 32);
      half8v qa = *(const half8v*)(Qp + kk * 32);
      half8v s = pa + qa;
#pragma unroll
      for (int j = 0; j < 8; ++j)
        s[j] = (s[j] > (_Float16)0.f) ? s[j] : (_Float16)0.f;
      a[tt][kk] = s;
    }
  }
  __syncthreads();  // waits for staging writes (and drains gathers)

  float4v acc[2][8];
#pragma unroll
  for (int tt = 0; tt < 2; ++tt)
#pragma unroll
    for (int j = 0; j < 8; ++j) acc[tt][j] = (float4v){0.f, 0.f, 0.f, 0.f};

#pragma unroll
  for (int kk = 0; kk < 4; ++kk) {
#pragma unroll
    for (int j = 0; j < 8; ++j) {
      half8v b = *(const half8v*)(WL + (((kk * 8 + j) * 64 + lane) << 3));
#pragma unroll
      for (int tt = 0; tt < 2; ++tt)
        acc[tt][j] = __builtin_amdgcn_mfma_f32_16x16x32_f16(a[tt][kk], b,
                                                            acc[tt][j], 0, 0, 0);
    }
  }

  // epilogue: second MLP layer + dot with w2, per tile
  float b1v[8], w2v[8];
#pragma unroll
  for (int j = 0; j < 8; ++j) {
    int n = j * 16 + lm;
    b1v[j] = b1[n];
    w2v[j] = w2[n];
  }
  float bb = b2[0];
#pragma unroll
  for (int tt = 0; tt < 2; ++tt) {
    float partv[4] = {0.f, 0.f, 0.f, 0.f};
#pragma unroll
    for (int j = 0; j < 8; ++j) {
#pragma unroll
      for (int r = 0; r < 4; ++r) {
        float e2 = fmaxf(acc[tt][j][r] + b1v[j], 0.f);
        partv[r] = fmaf(e2, w2v[j], partv[r]);
      }
    }
#pragma unroll
    for (int off = 1; off < 16; off <<= 1) {
#pragma unroll
      for (int r = 0; r < 4; ++r) partv[r] += __shfl_xor(partv[r], off, 64);
    }
    if (lm == 0) {
#pragma unroll
      for (int r = 0; r < 4; ++r) {
        int pe = base + tt * 16 + lq * 4 + r;
        if (pe < E) __builtin_nontemporal_store(partv[r] + bb, &tmpout[pe]);
      }
    }
  }
}

// ---------------- permute: out[e] = tmp[inv[e]] --------------------------
__global__ void k_perm(const float* __restrict__ tmp, const int* __restrict__ inv,
                       float* __restrict__ out, int E) {
  int e = blockIdx.x * 256 + threadIdx.x;
  if (e < E) {
    int idx = __builtin_nontemporal_load(&inv[e]);
    float v = tmp[idx];
    __builtin_nontemporal_store(v, &out[e]);
  }
}

// ---------------- host ---------------------------------------------------
extern "C" void kernel_launch(void* const* d_in, const int* in_sizes, int n_in,
                              void* d_out, int out_size, void* d_ws, size_t ws_size,
                              hipStream_t stream) {
  const float* x       = (const float*)d_in[0];
  const int*   ei      = (const int*)d_in[1];
  const float* convs_W = (const float*)d_in[2];
  const float* convs_b = (const float*)d_in[3];
  const float* fc0_W   = (const float*)d_in[4];
  const float* fc0_b   = (const float*)d_in[5];
  const float* fc1_W   = (const float*)d_in[6];
  const float* fc1_b   = (const float*)d_in[7];
  const float* fc2_W   = (const float*)d_in[8];
  const float* fc2_b   = (const float*)d_in[9];
  float* out = (float*)d_out;

  const int N = in_sizes[0] / C;        // 50000
  const int E = in_sizes[1] / 2;        // 1600000
  const int L = in_sizes[2] / (C * C);  // 8
  const int* row = ei;
  const int* col = ei + E;
  const int SB = (N + 255) / 256;       // 196 scan blocks (<=256)

  char* wp = (char*)d_ws;
  auto carve = [&](size_t bytes) {
    char* p = wp; wp += (bytes + 255) & ~(size_t)255; return p;
  };
  int*      cnt    = (int*)carve((size_t)N * 4);
  int*      part   = (int*)carve((size_t)SB * 4);
  int*      indptr = (int*)carve((size_t)(N + 1) * 4);
  int*      cursor = (int*)carve((size_t)N * 4);
  float*    dis    = (float*)carve((size_t)N * 4);
  int2*     emeta  = (int2*)carve((size_t)E * 8);
  int*      colcsr = (int*)carve((size_t)E * 4);
  int*      inv    = (int*)carve((size_t)E * 4);
  float*    tmpout = (float*)carve((size_t)E * 4);
  _Float16* Wf     = (_Float16*)carve((size_t)C * C * 2);
  _Float16* Wfh    = (_Float16*)carve((size_t)10 * C * C * 2);
  _Float16* Wfl    = (_Float16*)carve((size_t)10 * C * C * 2);
  _Float16* xh     = (_Float16*)carve((size_t)N * C * 2);
  _Float16* h0     = (_Float16*)carve((size_t)N * C * 2);
  _Float16* h1     = (_Float16*)carve((size_t)N * C * 2);
  _Float16* aggb   = (_Float16*)carve((size_t)N * C * 2);
  _Float16* Pm     = (_Float16*)carve((size_t)N * C * 2);
  _Float16* Qm     = (_Float16*)carve((size_t)N * C * 2);

  hipMemsetAsync(cnt, 0, (size_t)N * 4, stream);
  k_degree<<<(E + 255) / 256, 256, 0, stream>>>(col, cnt, E);
  k_scan_part<<<SB, 256, 0, stream>>>(cnt, part, N);
  k_scan_mid<<<1, 256, 0, stream>>>(part, SB);
  k_scan_fin<<<SB, 256, 0, stream>>>(cnt, part, dis, indptr, cursor, N);
  k_csrfill<<<(E + 255) / 256, 256, 0, stream>>>(row, col, dis, cursor,
                                                 emeta, inv, E);
  k_colfill<<<(N * 64 + 255) / 256, 256, 0, stream>>>(indptr, colcsr, N);
  k_prepwf<<<C * C / 256, 256, 0, stream>>>(fc1_W, Wf);
  k_prepw2<<<10 * C * C / 256, 256, 0, stream>>>(convs_W, fc0_W, Wfh, Wfl);
  k_cvt<<<(N * C / 4 + 255) / 256, 256, 0, stream>>>(x, xh, N * C / 4);

  int aggBlocks  = (N * 64 + 255) / 256;
  int gemmBlocks = (N + 63) / 64;
  const int MSZ = C * C;

  // layer 0 (no skip)
  k_agg<<<aggBlocks, 256, 0, stream>>>(xh, indptr, emeta, dis, aggb, N);
  k_gemm_f16<<<gemmBlocks, 256, 0, stream>>>(aggb, Wfh, Wfl, convs_b,
                                             nullptr, h0, N, 1);
  _Float16* hcur = h0; _Float16* hoth = h1;
  for (int l = 1; l < L; ++l) {
    k_agg<<<aggBlocks, 256, 0, stream>>>(hcur, indptr, emeta, dis, aggb, N);
    k_gemm_f16<<<gemmBlocks, 256, 0, stream>>>(aggb, Wfh + (size_t)l * MSZ,
                                               Wfl + (size_t)l * MSZ,
                                               convs_b + (size_t)l * C, hcur,
                                               hoth, N, 1);
    _Float16* tmp = hcur; hcur = hoth; hoth = tmp;
  }
  // edge MLP: P = h@fc0_W[:128], Q = h@fc0_W[128:] + b0 (one fused kernel)
  k_gemm_fc0<<<gemmBlocks, 256, 0, stream>>>(hcur, Wfh + (size_t)8 * MSZ,
                                             Wfl + (size_t)8 * MSZ, fc0_b,
                                             Pm, Qm, N);
  k_edge<<<(E + 127) / 128, 256, 0, stream>>>(Pm, Qm, emeta, colcsr, Wf, fc1_b,
                                              fc2_W, fc2_b, tmpout, E);
  k_perm<<<(E + 255) / 256, 256, 0, stream>>>(tmpout, inv, out, E);
}